// Round 3
// baseline (334.034 us; speedup 1.0000x reference)
//
#include <hip/hip_runtime.h>
#include <hip/hip_cooperative_groups.h>
#include <stdint.h>

namespace cg = cooperative_groups;

#define IN_F   11008
#define OUT_F  4096
#define TOPK_K 5504
#define NCACHE 64
#define MASK_WORDS 344   // 11008 / 32
#define NCHUNK 11        // ceil(11008 / 1024)
#define NBLK   256
#define NTHR   1024
#define ROWS_PER_BLOCK 16  // OUT_F / NBLK, one row per wave

// ws layout (bytes):
//   [0    , 1376) : topk mask bits (344 u32)
//   [1408 , 1412) : packed score u32, atomicMax of (inter<<6)|(63-row)
//   [1472 , 1476) : prefetch-stop flag

__device__ __forceinline__ unsigned absbits(float v) {
    return __float_as_uint(v) & 0x7fffffffu;
}

// ---------------------------------------------------------------------------
// Fused cooperative kernel, 256 blocks x 1024 threads (1 block/CU, 16 waves).
// Phase A: block 0 = exact radix-select + mask build (verified code);
//          blocks 1..255 = prefetch their own W slice into L2/L3 while HBM
//          is otherwise idle, stopping when block 0 raises the flag.
// Phase B: blocks 0..63 recall (bitmask intersection + packed atomicMax),
//          then ALL blocks build xs (mask path) and accumulate their 16 GEMV
//          rows speculatively (1 row/wave), result held in registers.
// Phase C: after grid sync, read score; topk path -> write out; cached path
//          (recall>=0.9, rare) -> rebuild xs from best row and re-accumulate.
// ---------------------------------------------------------------------------
__global__ __launch_bounds__(NTHR) void k_fused(const float* __restrict__ x,
                                                const float* __restrict__ W,
                                                const float* __restrict__ bias,
                                                const int* __restrict__ cached,
                                                float* __restrict__ out,
                                                unsigned* __restrict__ maskbits_g,
                                                unsigned* __restrict__ score_g,
                                                unsigned* __restrict__ flag_g) {
    __shared__ unsigned hist[16][256];   // per-wave private hists (select)
    __shared__ unsigned csum[256];
    __shared__ unsigned sh_T, sh_rem, sh_totEq;
    __shared__ unsigned waveEq[NCHUNK][16];
    __shared__ unsigned waveEqPre[NCHUNK][16];
    __shared__ unsigned rowbits[MASK_WORDS];   // recall
    __shared__ unsigned wsum[16];
    __shared__ __align__(16) float xs[IN_F];   // masked x for GEMV (44 KB)

    const int tid  = threadIdx.x;
    const int wv   = tid >> 6;
    const int lane = tid & 63;
    const int bid  = blockIdx.x;
    cg::grid_group grid = cg::this_grid();

    // ================= Phase A =================
    if (bid == 0) {
        if (tid == 0) {
            __hip_atomic_store(flag_g, 0u, __ATOMIC_RELAXED, __HIP_MEMORY_SCOPE_AGENT);
            *score_g = 0u;
        }
        const int nk = (tid < IN_F - 10 * 1024) ? NCHUNK : NCHUNK - 1;  // tid<768 -> 11 keys

        unsigned key[NCHUNK];
#pragma unroll
        for (int c = 0; c < NCHUNK; ++c) {
            key[c] = 0u;
            if (c < nk) key[c] = absbits(x[c * 1024 + tid]);
        }

        unsigned prefix = 0, maskHi = 0, remaining = TOPK_K;

        for (int pass = 3; pass >= 0; --pass) {
            const int sh = pass * 8;
            for (int b = tid; b < 16 * 256; b += 1024) ((unsigned*)hist)[b] = 0;
            __syncthreads();
#pragma unroll
            for (int c = 0; c < NCHUNK; ++c) {
                if (c < nk && (key[c] & maskHi) == prefix)
                    atomicAdd(&hist[wv][(key[c] >> sh) & 255], 1u);
            }
            __syncthreads();
            if (tid < 256) {            // merge 16 hists, conflict-free
                unsigned s = 0;
#pragma unroll
                for (int w = 0; w < 16; ++w) s += hist[w][tid];
                csum[tid] = s;
            }
            __syncthreads();
            if (wv == 0) {
                // lane l owns buckets [4l,4l+4); inclusive suffix-scan across lanes
                unsigned c0 = csum[4 * lane + 0], c1 = csum[4 * lane + 1];
                unsigned c2 = csum[4 * lane + 2], c3 = csum[4 * lane + 3];
                unsigned S = c0 + c1 + c2 + c3;
#pragma unroll
                for (int off = 1; off < 64; off <<= 1) {
                    unsigned v = __shfl_down(S, off, 64);
                    if (lane + off < 64) S += v;
                }
                unsigned Sn = __shfl_down(S, 1, 64);
                if (lane == 63) Sn = 0;
                unsigned t3 = Sn + c3;
                unsigned t2 = t3 + c2;
                unsigned t1 = t2 + c1;
                unsigned t0 = t1 + c0;
                unsigned rem = remaining;
                if (t3 >= rem && Sn < rem) { sh_T = prefix | ((unsigned)(4 * lane + 3) << sh); sh_rem = rem - Sn; }
                if (t2 >= rem && t3 < rem) { sh_T = prefix | ((unsigned)(4 * lane + 2) << sh); sh_rem = rem - t3; }
                if (t1 >= rem && t2 < rem) { sh_T = prefix | ((unsigned)(4 * lane + 1) << sh); sh_rem = rem - t2; }
                if (t0 >= rem && t1 < rem) { sh_T = prefix | ((unsigned)(4 * lane + 0) << sh); sh_rem = rem - t1; }
            }
            __syncthreads();
            prefix = sh_T;
            maskHi |= 0xffu << sh;
            remaining = sh_rem;
        }

        const unsigned T = prefix;
        const unsigned eqTake = remaining;

        unsigned gtm = 0, eqm = 0;
#pragma unroll
        for (int c = 0; c < NCHUNK; ++c) {
            if (c < nk) {
                if (key[c] > T)       gtm |= 1u << c;
                else if (key[c] == T) eqm |= 1u << c;
            }
        }
#pragma unroll
        for (int c = 0; c < NCHUNK; ++c) {
            unsigned long long bal = __ballot((eqm >> c) & 1u);
            if (lane == 0) waveEq[c][wv] = (unsigned)__popcll(bal);
        }
        __syncthreads();
        if (tid < 64) {
            unsigned s = 0;
            for (int p = lane; p < NCHUNK * 16; p += 64) s += waveEq[p >> 4][p & 15];
#pragma unroll
            for (int off = 32; off > 0; off >>= 1) s += __shfl_down(s, off, 64);
            if (lane == 0) sh_totEq = s;
        }
        __syncthreads();
        const bool fast = (sh_totEq == eqTake);
        if (!fast) {
            if (tid == 0) {
                unsigned run = 0;
                for (int c = 0; c < NCHUNK; ++c)
                    for (int w = 0; w < 16; ++w) { waveEqPre[c][w] = run; run += waveEq[c][w]; }
            }
            __syncthreads();
        }
#pragma unroll
        for (int c = 0; c < NCHUNK; ++c) {
            bool eq = (eqm >> c) & 1u;
            bool take;
            if (fast) {
                take = (((gtm >> c) & 1u) != 0u) || eq;
            } else {
                unsigned long long balEq = __ballot(eq);
                unsigned rank = waveEqPre[c][wv] + (unsigned)__popcll(balEq & ((1ull << lane) - 1ull));
                take = (((gtm >> c) & 1u) != 0u) || (eq && rank < eqTake);
            }
            unsigned long long balT = __ballot(take);
            int w0 = c * 32 + wv * 2;
            if (w0 < MASK_WORDS && lane == 0) {
                maskbits_g[w0]     = (unsigned)balT;
                maskbits_g[w0 + 1] = (unsigned)(balT >> 32);
            }
        }
        __syncthreads();
        if (tid == 0)   // stop prefetchers (visibility of mask itself comes from grid.sync)
            __hip_atomic_store(flag_g, 1u, __ATOMIC_RELAXED, __HIP_MEMORY_SCOPE_AGENT);
    } else {
        // prefetch this block's own contiguous W slice (rows bid*16..+15) into L2/L3
        const float4* wp = (const float4*)(W + (size_t)bid * ROWS_PER_BLOCK * IN_F);
        const int NCH = (ROWS_PER_BLOCK * IN_F / 4) / (2 * NTHR);   // 21 chunks of 32 KB
        for (int c = 0; c < NCH; ++c) {
            // first 4 chunks unconditional (flag starts as ws poison; block0's 0-store
            // needs a moment to land — worst case we just stop early, never wrong)
            if (c >= 4 && __hip_atomic_load(flag_g, __ATOMIC_RELAXED, __HIP_MEMORY_SCOPE_AGENT) != 0u)
                break;
            float4 a = wp[c * 2 * NTHR + tid];
            float4 b = wp[c * 2 * NTHR + NTHR + tid];
            asm volatile("" :: "v"(a.x), "v"(a.y), "v"(a.z), "v"(a.w));
            asm volatile("" :: "v"(b.x), "v"(b.y), "v"(b.z), "v"(b.w));
        }
    }

    grid.sync();

    // ================= Phase B =================
    if (bid < NCACHE) {   // recall for cached row = bid
        for (int w = tid; w < MASK_WORDS; w += NTHR) rowbits[w] = 0;
        __syncthreads();
        const int4* ci4 = (const int4*)(cached + (size_t)bid * TOPK_K);
        for (int t = tid; t < TOPK_K / 4; t += NTHR) {
            int4 v = ci4[t];
            atomicOr(&rowbits[v.x >> 5], 1u << (v.x & 31));
            atomicOr(&rowbits[v.y >> 5], 1u << (v.y & 31));
            atomicOr(&rowbits[v.z >> 5], 1u << (v.z & 31));
            atomicOr(&rowbits[v.w >> 5], 1u << (v.w & 31));
        }
        __syncthreads();
        unsigned cnt = 0;
        for (int w = tid; w < MASK_WORDS; w += NTHR) cnt += __popc(rowbits[w] & maskbits_g[w]);
        for (int off = 32; off > 0; off >>= 1) cnt += __shfl_down(cnt, off, 64);
        if (lane == 0) wsum[wv] = cnt;
        __syncthreads();
        if (tid == 0) {
            unsigned tot = 0;
#pragma unroll
            for (int w = 0; w < 16; ++w) tot += wsum[w];
            atomicMax(score_g, (tot << 6) | (unsigned)(63 - bid));
        }
    }

    // xs = mask .* x (speculative topk path)
    {
        const float4* x4 = (const float4*)x;
        for (int j = tid; j < IN_F / 4; j += NTHR) {
            float4 xv = x4[j];
            int base = j * 4;
            unsigned wbits = maskbits_g[base >> 5];
            int sh = base & 31;
            xs[base + 0] = xv.x * (float)((wbits >> (sh + 0)) & 1u);
            xs[base + 1] = xv.y * (float)((wbits >> (sh + 1)) & 1u);
            xs[base + 2] = xv.z * (float)((wbits >> (sh + 2)) & 1u);
            xs[base + 3] = xv.w * (float)((wbits >> (sh + 3)) & 1u);
        }
    }
    __syncthreads();

    const int row = bid * ROWS_PER_BLOCK + wv;   // one GEMV row per wave
    const float4* wrow = (const float4*)(W + (size_t)row * IN_F);
    const float4* xs4  = (const float4*)xs;

    float acc = 0.f;
#pragma unroll 4
    for (int j = lane; j < IN_F / 4; j += 64) {   // exactly 43 iters/lane
        float4 a  = wrow[j];
        float4 xv = xs4[j];
        acc += xv.x * a.x + xv.y * a.y + xv.z * a.z + xv.w * a.w;
    }
    for (int off = 32; off > 0; off >>= 1) acc += __shfl_down(acc, off, 64);

    grid.sync();

    // ================= Phase C =================
    unsigned score = *score_g;
    bool useCache = ((float)(score >> 6) / (float)TOPK_K) >= 0.9f;
    if (!useCache) {
        if (lane == 0) out[row] = acc + bias[row];
    } else {
        // rare exact path: xs[i] = multiplicity(i in best row) * x[i]
        int best = 63 - (int)(score & 63u);
        __syncthreads();
        for (int i = tid; i < IN_F; i += NTHR) xs[i] = 0.f;
        __syncthreads();
        const int* ci = cached + (size_t)best * TOPK_K;
        for (int t = tid; t < TOPK_K; t += NTHR) {
            int idx = ci[t];
            atomicAdd(&xs[idx], x[idx]);   // duplicates accumulate -> count*x
        }
        __syncthreads();
        float acc2 = 0.f;
#pragma unroll 4
        for (int j = lane; j < IN_F / 4; j += 64) {
            float4 a  = wrow[j];
            float4 xv = xs4[j];
            acc2 += xv.x * a.x + xv.y * a.y + xv.z * a.z + xv.w * a.w;
        }
        for (int off = 32; off > 0; off >>= 1) acc2 += __shfl_down(acc2, off, 64);
        if (lane == 0) out[row] = acc2 + bias[row];
    }
}

extern "C" void kernel_launch(void* const* d_in, const int* in_sizes, int n_in,
                              void* d_out, int out_size, void* d_ws, size_t ws_size,
                              hipStream_t stream) {
    const float* x      = (const float*)d_in[0];
    const float* W      = (const float*)d_in[1];
    const float* bias   = (const float*)d_in[2];
    const int*   cached = (const int*)d_in[3];
    float* out = (float*)d_out;

    char* ws = (char*)d_ws;
    unsigned* maskbits = (unsigned*)(ws + 0);
    unsigned* score    = (unsigned*)(ws + 1408);
    unsigned* flag     = (unsigned*)(ws + 1472);

    void* args[] = { (void*)&x, (void*)&W, (void*)&bias, (void*)&cached,
                     (void*)&out, (void*)&maskbits, (void*)&score, (void*)&flag };
    hipLaunchCooperativeKernel((const void*)k_fused, dim3(NBLK), dim3(NTHR),
                               args, 0, stream);
}

// Round 4
// 266.590 us; speedup vs baseline: 1.2530x; 1.2530x over previous
//
#include <hip/hip_runtime.h>
#include <stdint.h>

#define IN_F   11008
#define OUT_F  4096
#define TOPK_K 5504
#define NCACHE 64
#define MASK_WORDS 344   // 11008 / 32
#define NCHUNK 11        // ceil(11008 / 1024)
#define ROWS_PER_BLOCK 16
#define GEMV_THREADS   512

// ws layout (bytes):
//   [0    , 1376) : topk mask bits (344 u32)
//   [1472 , 1476) : packed score u32, atomicMax of (inter<<6)|(63-row)
//   [1476 , 1480) : prefetch-stop flag
//   [1480 , 1484) : recall-done counter
// (score/flag/done zeroed by hipMemsetAsync before launch A)

__device__ __forceinline__ unsigned absbits(float v) {
    return __float_as_uint(v) & 0x7fffffffu;
}

// ---------------------------------------------------------------------------
// A: block 0 = exact radix-select of the 5504-th largest |x| + mask build
//    (verified code, unchanged). blocks 1..255 = stream their own 704KB W
//    slice into L2/L3 while HBM is otherwise idle; stop when block 0 raises
//    the flag (hint only — no correctness dependence). 256 blocks x 1024.
// ---------------------------------------------------------------------------
__global__ __launch_bounds__(1024) void k_select_prefetch(const float* __restrict__ x,
                                                          const float* __restrict__ W,
                                                          unsigned* __restrict__ maskbits_g,
                                                          unsigned* __restrict__ flag_g) {
    __shared__ unsigned hist[16][256];   // per-wave private hists
    __shared__ unsigned csum[256];
    __shared__ unsigned sh_T, sh_rem, sh_totEq;
    __shared__ unsigned waveEq[NCHUNK][16];
    __shared__ unsigned waveEqPre[NCHUNK][16];

    const int tid  = threadIdx.x;
    const int wv   = tid >> 6;
    const int lane = tid & 63;
    const int bid  = blockIdx.x;

    if (bid != 0) {
        // prefetch W rows [bid*16, bid*16+16) into L2/L3; gemv re-reads them
        const float4* wp = (const float4*)(W + (size_t)bid * (ROWS_PER_BLOCK * IN_F));
        const int NCH = (ROWS_PER_BLOCK * IN_F / 4) / (2 * 1024);   // 21 chunks of 32 KB
        for (int c = 0; c < NCH; ++c) {
            if (c >= 1 && __hip_atomic_load(flag_g, __ATOMIC_RELAXED, __HIP_MEMORY_SCOPE_AGENT) != 0u)
                break;
            float4 a = wp[c * 2048 + tid];
            float4 b = wp[c * 2048 + 1024 + tid];
            asm volatile("" :: "v"(a.x), "v"(a.y), "v"(a.z), "v"(a.w));
            asm volatile("" :: "v"(b.x), "v"(b.y), "v"(b.z), "v"(b.w));
        }
        return;
    }

    // ---- block 0: verified radix-select ----
    const int nk = (tid < IN_F - 10 * 1024) ? NCHUNK : NCHUNK - 1;  // tid<768 -> 11 keys

    unsigned key[NCHUNK];
#pragma unroll
    for (int c = 0; c < NCHUNK; ++c) {
        key[c] = 0u;
        if (c < nk) key[c] = absbits(x[c * 1024 + tid]);
    }

    unsigned prefix = 0, maskHi = 0, remaining = TOPK_K;

    for (int pass = 3; pass >= 0; --pass) {
        const int sh = pass * 8;
        for (int b = tid; b < 16 * 256; b += 1024) ((unsigned*)hist)[b] = 0;
        __syncthreads();
#pragma unroll
        for (int c = 0; c < NCHUNK; ++c) {
            if (c < nk && (key[c] & maskHi) == prefix)
                atomicAdd(&hist[wv][(key[c] >> sh) & 255], 1u);
        }
        __syncthreads();
        if (tid < 256) {            // merge 16 hists, conflict-free
            unsigned s = 0;
#pragma unroll
            for (int w = 0; w < 16; ++w) s += hist[w][tid];
            csum[tid] = s;
        }
        __syncthreads();
        if (wv == 0) {
            // lane l owns buckets [4l,4l+4); inclusive suffix-scan across lanes
            unsigned c0 = csum[4 * lane + 0], c1 = csum[4 * lane + 1];
            unsigned c2 = csum[4 * lane + 2], c3 = csum[4 * lane + 3];
            unsigned S = c0 + c1 + c2 + c3;
#pragma unroll
            for (int off = 1; off < 64; off <<= 1) {
                unsigned v = __shfl_down(S, off, 64);
                if (lane + off < 64) S += v;
            }
            unsigned Sn = __shfl_down(S, 1, 64);
            if (lane == 63) Sn = 0;
            unsigned t3 = Sn + c3;
            unsigned t2 = t3 + c2;
            unsigned t1 = t2 + c1;
            unsigned t0 = t1 + c0;
            unsigned rem = remaining;
            if (t3 >= rem && Sn < rem) { sh_T = prefix | ((unsigned)(4 * lane + 3) << sh); sh_rem = rem - Sn; }
            if (t2 >= rem && t3 < rem) { sh_T = prefix | ((unsigned)(4 * lane + 2) << sh); sh_rem = rem - t3; }
            if (t1 >= rem && t2 < rem) { sh_T = prefix | ((unsigned)(4 * lane + 1) << sh); sh_rem = rem - t2; }
            if (t0 >= rem && t1 < rem) { sh_T = prefix | ((unsigned)(4 * lane + 0) << sh); sh_rem = rem - t1; }
        }
        __syncthreads();
        prefix = sh_T;
        maskHi |= 0xffu << sh;
        remaining = sh_rem;
    }

    const unsigned T = prefix;
    const unsigned eqTake = remaining;

    unsigned gtm = 0, eqm = 0;
#pragma unroll
    for (int c = 0; c < NCHUNK; ++c) {
        if (c < nk) {
            if (key[c] > T)       gtm |= 1u << c;
            else if (key[c] == T) eqm |= 1u << c;
        }
    }
#pragma unroll
    for (int c = 0; c < NCHUNK; ++c) {
        unsigned long long bal = __ballot((eqm >> c) & 1u);
        if (lane == 0) waveEq[c][wv] = (unsigned)__popcll(bal);
    }
    __syncthreads();
    if (tid < 64) {
        unsigned s = 0;
        for (int p = lane; p < NCHUNK * 16; p += 64) s += waveEq[p >> 4][p & 15];
#pragma unroll
        for (int off = 32; off > 0; off >>= 1) s += __shfl_down(s, off, 64);
        if (lane == 0) sh_totEq = s;
    }
    __syncthreads();
    const bool fast = (sh_totEq == eqTake);
    if (!fast) {
        if (tid == 0) {
            unsigned run = 0;
            for (int c = 0; c < NCHUNK; ++c)
                for (int w = 0; w < 16; ++w) { waveEqPre[c][w] = run; run += waveEq[c][w]; }
        }
        __syncthreads();
    }
#pragma unroll
    for (int c = 0; c < NCHUNK; ++c) {
        bool eq = (eqm >> c) & 1u;
        bool take;
        if (fast) {
            take = (((gtm >> c) & 1u) != 0u) || eq;
        } else {
            unsigned long long balEq = __ballot(eq);
            unsigned rank = waveEqPre[c][wv] + (unsigned)__popcll(balEq & ((1ull << lane) - 1ull));
            take = (((gtm >> c) & 1u) != 0u) || (eq && rank < eqTake);
        }
        unsigned long long balT = __ballot(take);
        int w0 = c * 32 + wv * 2;            // this wave-chunk owns words w0, w0+1
        if (w0 < MASK_WORDS && lane == 0) {
            maskbits_g[w0]     = (unsigned)balT;
            maskbits_g[w0 + 1] = (unsigned)(balT >> 32);
        }
    }
    __syncthreads();
    if (tid == 0)   // stop prefetchers (hint; mask visibility comes from kernel boundary)
        __hip_atomic_store(flag_g, 1u, __ATOMIC_RELAXED, __HIP_MEMORY_SCOPE_AGENT);
}

// ---------------------------------------------------------------------------
// B: 320 blocks x 512. Blocks 0..63: recall for cached row bid (bitmask
//    intersection + packed atomicMax), then release-increment done counter.
//    Blocks 64..319: GEMV (R2-verified shape: 2 rows/wave, 16 rows/block,
//    unroll 4) computed speculatively on the mask path; epilogue acquire-spins
//    on done==64 (recall finished ~35us earlier), then writes out — or, on
//    the rare cached path, rebuilds xs from the best row and recomputes.
//    All 320 blocks fit co-resident (LDS 45KB -> 3 blocks/CU) -> no deadlock.
// ---------------------------------------------------------------------------
__global__ __launch_bounds__(GEMV_THREADS) void k_recall_gemv(const float* __restrict__ x,
                                                              const float* __restrict__ W,
                                                              const float* __restrict__ bias,
                                                              const int* __restrict__ cached,
                                                              const unsigned* __restrict__ maskbits_g,
                                                              unsigned* __restrict__ score_g,
                                                              unsigned* __restrict__ done_g,
                                                              float* __restrict__ out) {
    __shared__ __align__(16) float xs[IN_F];   // 44 KB
    __shared__ unsigned rowbits[MASK_WORDS];
    __shared__ unsigned wsum[8];
    const int tid  = threadIdx.x;
    const int wv   = tid >> 6;
    const int lane = tid & 63;
    const int bid  = blockIdx.x;

    if (bid < NCACHE) {   // ---- recall for cached row r = bid ----
        for (int w = tid; w < MASK_WORDS; w += GEMV_THREADS) rowbits[w] = 0;
        __syncthreads();
        const int4* ci4 = (const int4*)(cached + (size_t)bid * TOPK_K);
        for (int t = tid; t < TOPK_K / 4; t += GEMV_THREADS) {
            int4 v = ci4[t];
            atomicOr(&rowbits[v.x >> 5], 1u << (v.x & 31));
            atomicOr(&rowbits[v.y >> 5], 1u << (v.y & 31));
            atomicOr(&rowbits[v.z >> 5], 1u << (v.z & 31));
            atomicOr(&rowbits[v.w >> 5], 1u << (v.w & 31));
        }
        __syncthreads();
        unsigned cnt = 0;
        for (int w = tid; w < MASK_WORDS; w += GEMV_THREADS) cnt += __popc(rowbits[w] & maskbits_g[w]);
        for (int off = 32; off > 0; off >>= 1) cnt += __shfl_down(cnt, off, 64);
        if (lane == 0) wsum[wv] = cnt;
        __syncthreads();
        if (tid == 0) {
            unsigned tot = 0;
#pragma unroll
            for (int w = 0; w < 8; ++w) tot += wsum[w];
            atomicMax(score_g, (tot << 6) | (unsigned)(63 - bid));
            __hip_atomic_fetch_add(done_g, 1u, __ATOMIC_RELEASE, __HIP_MEMORY_SCOPE_AGENT);
        }
        return;
    }

    // ---- GEMV, speculative mask path ----
    const int g = bid - NCACHE;
    const float4* x4 = (const float4*)x;
    for (int j = tid; j < IN_F / 4; j += GEMV_THREADS) {
        float4 xv = x4[j];
        int base = j * 4;
        unsigned wbits = maskbits_g[base >> 5];
        int sh = base & 31;
        xs[base + 0] = xv.x * (float)((wbits >> (sh + 0)) & 1u);
        xs[base + 1] = xv.y * (float)((wbits >> (sh + 1)) & 1u);
        xs[base + 2] = xv.z * (float)((wbits >> (sh + 2)) & 1u);
        xs[base + 3] = xv.w * (float)((wbits >> (sh + 3)) & 1u);
    }
    __syncthreads();

    const int row0 = g * ROWS_PER_BLOCK + wv * 2;
    const int row1 = row0 + 1;
    const float4* w0p = (const float4*)(W + (size_t)row0 * IN_F);
    const float4* w1p = (const float4*)(W + (size_t)row1 * IN_F);
    const float4* xs4 = (const float4*)xs;

    float acc0 = 0.f, acc1 = 0.f;
#pragma unroll 4
    for (int j = lane; j < IN_F / 4; j += 64) {   // exactly 43 iters/lane
        float4 xv = xs4[j];
        float4 a  = w0p[j];
        float4 b  = w1p[j];
        acc0 += xv.x * a.x + xv.y * a.y + xv.z * a.z + xv.w * a.w;
        acc1 += xv.x * b.x + xv.y * b.y + xv.z * b.z + xv.w * b.w;
    }
    for (int off = 32; off > 0; off >>= 1) {
        acc0 += __shfl_down(acc0, off, 64);
        acc1 += __shfl_down(acc1, off, 64);
    }

    // wait for all 64 recall blocks (they finished long ago in practice)
    if (tid == 0) {
        while (__hip_atomic_load(done_g, __ATOMIC_ACQUIRE, __HIP_MEMORY_SCOPE_AGENT) < NCACHE)
            __builtin_amdgcn_s_sleep(2);
    }
    __syncthreads();

    unsigned score = *score_g;
    bool useCache = ((float)(score >> 6) / (float)TOPK_K) >= 0.9f;
    if (!useCache) {
        if (lane == 0) {
            out[row0] = acc0 + bias[row0];
            out[row1] = acc1 + bias[row1];
        }
    } else {
        // rare exact path: xs[i] = multiplicity(i in best row) * x[i]
        int best = 63 - (int)(score & 63u);
        __syncthreads();
        for (int i = tid; i < IN_F; i += GEMV_THREADS) xs[i] = 0.f;
        __syncthreads();
        const int* ci = cached + (size_t)best * TOPK_K;
        for (int t = tid; t < TOPK_K; t += GEMV_THREADS) {
            int idx = ci[t];
            atomicAdd(&xs[idx], x[idx]);   // duplicates accumulate -> count*x
        }
        __syncthreads();
        float a0 = 0.f, a1 = 0.f;
#pragma unroll 4
        for (int j = lane; j < IN_F / 4; j += 64) {
            float4 xv = xs4[j];
            float4 a  = w0p[j];
            float4 b  = w1p[j];
            a0 += xv.x * a.x + xv.y * a.y + xv.z * a.z + xv.w * a.w;
            a1 += xv.x * b.x + xv.y * b.y + xv.z * b.z + xv.w * b.w;
        }
        for (int off = 32; off > 0; off >>= 1) {
            a0 += __shfl_down(a0, off, 64);
            a1 += __shfl_down(a1, off, 64);
        }
        if (lane == 0) {
            out[row0] = a0 + bias[row0];
            out[row1] = a1 + bias[row1];
        }
    }
}

extern "C" void kernel_launch(void* const* d_in, const int* in_sizes, int n_in,
                              void* d_out, int out_size, void* d_ws, size_t ws_size,
                              hipStream_t stream) {
    const float* x      = (const float*)d_in[0];
    const float* W      = (const float*)d_in[1];
    const float* bias   = (const float*)d_in[2];
    const int*   cached = (const int*)d_in[3];
    float* out = (float*)d_out;

    char* ws = (char*)d_ws;
    unsigned* maskbits = (unsigned*)(ws + 0);
    unsigned* score    = (unsigned*)(ws + 1472);
    unsigned* flag     = (unsigned*)(ws + 1476);
    unsigned* done     = (unsigned*)(ws + 1480);

    hipMemsetAsync(ws + 1472, 0, 12, stream);   // score, flag, done
    k_select_prefetch<<<256, 1024, 0, stream>>>(x, W, maskbits, flag);
    k_recall_gemv<<<NCACHE + OUT_F / ROWS_PER_BLOCK, GEMV_THREADS, 0, stream>>>(
        x, W, bias, cached, maskbits, score, done, out);
}

// Round 5
// 265.528 us; speedup vs baseline: 1.2580x; 1.0040x over previous
//
#include <hip/hip_runtime.h>
#include <stdint.h>

#define IN_F   11008
#define OUT_F  4096
#define TOPK_K 5504
#define NCACHE 64
#define MASK_WORDS 344   // 11008 / 32
#define NTHR   512
#define NCHUNK 22        // ceil(11008 / 512)
#define ROWS_PER_BLOCK 16
#define NGEMV  (OUT_F / ROWS_PER_BLOCK)   // 256
#define NBLK   (1 + NCACHE + NGEMV)       // 321

// ws layout (bytes):
//   [0    , 1376) : topk mask bits (344 u32)
//   [1472 , 1476) : packed score u32, atomicMax of (inter<<6)|(63-row)
//   [1476 , 1480) : mask-ready flag (release by block 0)
//   [1480 , 1484) : recall-done counter
// (score/flag/done zeroed by hipMemsetAsync before launch)

__device__ __forceinline__ unsigned absbits(float v) {
    return __float_as_uint(v) & 0x7fffffffu;
}

// ---------------------------------------------------------------------------
// Single fused kernel, 321 blocks x 512 threads, all co-resident by resource
// math (LDS 54.8KB -> 2 blocks/CU; VGPR<=128 via launch_bounds -> 16 waves/CU).
//   block 0      : exact radix-select + mask build, then release mask flag.
//   blocks 1..64 : build rowbits for cached row (bid-1) during select shadow,
//                  acquire flag, intersect -> packed atomicMax score,
//                  release-increment done.
//   blocks 65..320: prefetch own 16-row W slice (stop on flag), acquire flag,
//                  xs = mask.*x, GEMV 2 rows/wave (R4-verified loop), spin
//                  done==64, epilogue (mask path or rare exact cached path).
// Dependency DAG acyclic; no reliance on dispatch order.
// ---------------------------------------------------------------------------
__global__ __launch_bounds__(NTHR, 4) void k_all(const float* __restrict__ x,
                                                 const float* __restrict__ W,
                                                 const float* __restrict__ bias,
                                                 const int* __restrict__ cached,
                                                 float* __restrict__ out,
                                                 unsigned* __restrict__ maskbits_g,
                                                 unsigned* __restrict__ score_g,
                                                 unsigned* __restrict__ flag_g,
                                                 unsigned* __restrict__ done_g) {
    __shared__ unsigned hist[8][256];    // select: per-wave private hists (8KB)
    __shared__ unsigned csum[256];
    __shared__ unsigned sh_T, sh_rem, sh_totEq;
    __shared__ unsigned waveEq[NCHUNK][8];
    __shared__ unsigned waveEqPre[NCHUNK][8];
    __shared__ unsigned rowbits[MASK_WORDS];   // recall
    __shared__ unsigned wsum[8];
    __shared__ __align__(16) float xs[IN_F];   // gemv (44KB)

    const int tid  = threadIdx.x;
    const int wv   = tid >> 6;
    const int lane = tid & 63;
    const int bid  = blockIdx.x;

    // ===================== block 0: radix-select =====================
    if (bid == 0) {
        const int nk = (tid < 256) ? NCHUNK : NCHUNK - 1;   // 11008 = 21*512 + 256

        unsigned key[NCHUNK];
#pragma unroll
        for (int c = 0; c < NCHUNK; ++c) {
            key[c] = 0u;
            if (c < nk) key[c] = absbits(x[c * NTHR + tid]);
        }

        unsigned prefix = 0, maskHi = 0, remaining = TOPK_K;

        for (int pass = 3; pass >= 0; --pass) {
            const int sh = pass * 8;
            for (int b = tid; b < 8 * 256; b += NTHR) ((unsigned*)hist)[b] = 0;
            __syncthreads();
#pragma unroll
            for (int c = 0; c < NCHUNK; ++c) {
                if (c < nk && (key[c] & maskHi) == prefix)
                    atomicAdd(&hist[wv][(key[c] >> sh) & 255], 1u);
            }
            __syncthreads();
            if (tid < 256) {          // merge 8 hists, conflict-free
                unsigned s = 0;
#pragma unroll
                for (int w = 0; w < 8; ++w) s += hist[w][tid];
                csum[tid] = s;
            }
            __syncthreads();
            if (wv == 0) {
                // lane l owns buckets [4l,4l+4); inclusive suffix-scan across lanes
                unsigned c0 = csum[4 * lane + 0], c1 = csum[4 * lane + 1];
                unsigned c2 = csum[4 * lane + 2], c3 = csum[4 * lane + 3];
                unsigned S = c0 + c1 + c2 + c3;
#pragma unroll
                for (int off = 1; off < 64; off <<= 1) {
                    unsigned v = __shfl_down(S, off, 64);
                    if (lane + off < 64) S += v;
                }
                unsigned Sn = __shfl_down(S, 1, 64);
                if (lane == 63) Sn = 0;
                unsigned t3 = Sn + c3;
                unsigned t2 = t3 + c2;
                unsigned t1 = t2 + c1;
                unsigned t0 = t1 + c0;
                unsigned rem = remaining;
                if (t3 >= rem && Sn < rem) { sh_T = prefix | ((unsigned)(4 * lane + 3) << sh); sh_rem = rem - Sn; }
                if (t2 >= rem && t3 < rem) { sh_T = prefix | ((unsigned)(4 * lane + 2) << sh); sh_rem = rem - t3; }
                if (t1 >= rem && t2 < rem) { sh_T = prefix | ((unsigned)(4 * lane + 1) << sh); sh_rem = rem - t2; }
                if (t0 >= rem && t1 < rem) { sh_T = prefix | ((unsigned)(4 * lane + 0) << sh); sh_rem = rem - t1; }
            }
            __syncthreads();
            prefix = sh_T;
            maskHi |= 0xffu << sh;
            remaining = sh_rem;
        }

        const unsigned T = prefix;
        const unsigned eqTake = remaining;

        unsigned gtm = 0, eqm = 0;
#pragma unroll
        for (int c = 0; c < NCHUNK; ++c) {
            if (c < nk) {
                if (key[c] > T)       gtm |= 1u << c;
                else if (key[c] == T) eqm |= 1u << c;
            }
        }
#pragma unroll
        for (int c = 0; c < NCHUNK; ++c) {
            unsigned long long bal = __ballot((eqm >> c) & 1u);
            if (lane == 0) waveEq[c][wv] = (unsigned)__popcll(bal);
        }
        __syncthreads();
        if (tid < 64) {
            unsigned s = 0;
            for (int p = lane; p < NCHUNK * 8; p += 64) s += waveEq[p >> 3][p & 7];
#pragma unroll
            for (int off = 32; off > 0; off >>= 1) s += __shfl_down(s, off, 64);
            if (lane == 0) sh_totEq = s;
        }
        __syncthreads();
        const bool fast = (sh_totEq == eqTake);
        if (!fast) {
            if (tid == 0) {
                unsigned run = 0;
                for (int c = 0; c < NCHUNK; ++c)
                    for (int w = 0; w < 8; ++w) { waveEqPre[c][w] = run; run += waveEq[c][w]; }
            }
            __syncthreads();
        }
#pragma unroll
        for (int c = 0; c < NCHUNK; ++c) {
            bool eq = (eqm >> c) & 1u;
            bool take;
            if (fast) {
                take = (((gtm >> c) & 1u) != 0u) || eq;
            } else {
                unsigned long long balEq = __ballot(eq);
                unsigned rank = waveEqPre[c][wv] + (unsigned)__popcll(balEq & ((1ull << lane) - 1ull));
                take = (((gtm >> c) & 1u) != 0u) || (eq && rank < eqTake);
            }
            unsigned long long balT = __ballot(take);
            int w0 = c * 16 + wv * 2;          // chunk c covers words [c*16, c*16+16)
            if (w0 < MASK_WORDS && lane == 0) {
                maskbits_g[w0]     = (unsigned)balT;
                maskbits_g[w0 + 1] = (unsigned)(balT >> 32);
            }
        }
        __syncthreads();
        if (tid == 0) {
            __threadfence();   // make maskbits visible device-wide, then release flag
            __hip_atomic_store(flag_g, 1u, __ATOMIC_RELEASE, __HIP_MEMORY_SCOPE_AGENT);
        }
        return;
    }

    // ===================== blocks 1..64: recall =====================
    if (bid <= NCACHE) {
        const int r = bid - 1;
        // build rowbits during the select shadow (mask-independent)
        for (int w = tid; w < MASK_WORDS; w += NTHR) rowbits[w] = 0;
        __syncthreads();
        const int4* ci4 = (const int4*)(cached + (size_t)r * TOPK_K);
        for (int t = tid; t < TOPK_K / 4; t += NTHR) {
            int4 v = ci4[t];
            atomicOr(&rowbits[v.x >> 5], 1u << (v.x & 31));
            atomicOr(&rowbits[v.y >> 5], 1u << (v.y & 31));
            atomicOr(&rowbits[v.z >> 5], 1u << (v.z & 31));
            atomicOr(&rowbits[v.w >> 5], 1u << (v.w & 31));
        }
        __syncthreads();
        if (tid == 0) {
            while (__hip_atomic_load(flag_g, __ATOMIC_ACQUIRE, __HIP_MEMORY_SCOPE_AGENT) == 0u)
                __builtin_amdgcn_s_sleep(8);
        }
        __syncthreads();
        unsigned cnt = 0;
        for (int w = tid; w < MASK_WORDS; w += NTHR) cnt += __popc(rowbits[w] & maskbits_g[w]);
        for (int off = 32; off > 0; off >>= 1) cnt += __shfl_down(cnt, off, 64);
        if (lane == 0) wsum[wv] = cnt;
        __syncthreads();
        if (tid == 0) {
            unsigned tot = 0;
#pragma unroll
            for (int w = 0; w < 8; ++w) tot += wsum[w];
            atomicMax(score_g, (tot << 6) | (unsigned)(63 - r));
            __hip_atomic_fetch_add(done_g, 1u, __ATOMIC_RELEASE, __HIP_MEMORY_SCOPE_AGENT);
        }
        return;
    }

    // ===================== blocks 65..320: GEMV =====================
    const int g = bid - 1 - NCACHE;                  // 0..255
    const float4* wp = (const float4*)(W + (size_t)g * (ROWS_PER_BLOCK * IN_F));

    // prefetch own W slice into L2/L3 while select runs (stop on flag; hint only)
    {
        const int NCH = (ROWS_PER_BLOCK * IN_F / 4) / (2 * NTHR);   // 43 chunks of 16KB
        for (int c = 0; c < NCH; ++c) {
            if (c >= 1 && __hip_atomic_load(flag_g, __ATOMIC_RELAXED, __HIP_MEMORY_SCOPE_AGENT) != 0u)
                break;
            float4 a = wp[c * 2 * NTHR + tid];
            float4 b = wp[c * 2 * NTHR + NTHR + tid];
            asm volatile("" :: "v"(a.x), "v"(a.y), "v"(a.z), "v"(a.w));
            asm volatile("" :: "v"(b.x), "v"(b.y), "v"(b.z), "v"(b.w));
        }
    }

    // wait for mask
    if (tid == 0) {
        while (__hip_atomic_load(flag_g, __ATOMIC_ACQUIRE, __HIP_MEMORY_SCOPE_AGENT) == 0u)
            __builtin_amdgcn_s_sleep(8);
    }
    __syncthreads();

    // xs = mask .* x (speculative topk path)
    {
        const float4* x4 = (const float4*)x;
        for (int j = tid; j < IN_F / 4; j += NTHR) {
            float4 xv = x4[j];
            int base = j * 4;
            unsigned wbits = maskbits_g[base >> 5];
            int sh = base & 31;
            xs[base + 0] = xv.x * (float)((wbits >> (sh + 0)) & 1u);
            xs[base + 1] = xv.y * (float)((wbits >> (sh + 1)) & 1u);
            xs[base + 2] = xv.z * (float)((wbits >> (sh + 2)) & 1u);
            xs[base + 3] = xv.w * (float)((wbits >> (sh + 3)) & 1u);
        }
    }
    __syncthreads();

    const int row0 = g * ROWS_PER_BLOCK + wv * 2;
    const int row1 = row0 + 1;
    const float4* w0p = (const float4*)(W + (size_t)row0 * IN_F);
    const float4* w1p = (const float4*)(W + (size_t)row1 * IN_F);
    const float4* xs4 = (const float4*)xs;

    float acc0 = 0.f, acc1 = 0.f;
#pragma unroll 4
    for (int j = lane; j < IN_F / 4; j += 64) {   // exactly 43 iters/lane
        float4 xv = xs4[j];
        float4 a  = w0p[j];
        float4 b  = w1p[j];
        acc0 += xv.x * a.x + xv.y * a.y + xv.z * a.z + xv.w * a.w;
        acc1 += xv.x * b.x + xv.y * b.y + xv.z * b.z + xv.w * b.w;
    }
    for (int off = 32; off > 0; off >>= 1) {
        acc0 += __shfl_down(acc0, off, 64);
        acc1 += __shfl_down(acc1, off, 64);
    }

    // wait for all 64 recall blocks (finished long ago in practice)
    if (tid == 0) {
        while (__hip_atomic_load(done_g, __ATOMIC_ACQUIRE, __HIP_MEMORY_SCOPE_AGENT) < NCACHE)
            __builtin_amdgcn_s_sleep(2);
    }
    __syncthreads();

    unsigned score = *score_g;
    bool useCache = ((float)(score >> 6) / (float)TOPK_K) >= 0.9f;
    if (!useCache) {
        if (lane == 0) {
            out[row0] = acc0 + bias[row0];
            out[row1] = acc1 + bias[row1];
        }
    } else {
        // rare exact path: xs[i] = multiplicity(i in best row) * x[i]
        int best = 63 - (int)(score & 63u);
        __syncthreads();
        for (int i = tid; i < IN_F; i += NTHR) xs[i] = 0.f;
        __syncthreads();
        const int* ci = cached + (size_t)best * TOPK_K;
        for (int t = tid; t < TOPK_K; t += NTHR) {
            int idx = ci[t];
            atomicAdd(&xs[idx], x[idx]);   // duplicates accumulate -> count*x
        }
        __syncthreads();
        float a0 = 0.f, a1 = 0.f;
#pragma unroll 4
        for (int j = lane; j < IN_F / 4; j += 64) {
            float4 xv = xs4[j];
            float4 a  = w0p[j];
            float4 b  = w1p[j];
            a0 += xv.x * a.x + xv.y * a.y + xv.z * a.z + xv.w * a.w;
            a1 += xv.x * b.x + xv.y * b.y + xv.z * b.z + xv.w * b.w;
        }
        for (int off = 32; off > 0; off >>= 1) {
            a0 += __shfl_down(a0, off, 64);
            a1 += __shfl_down(a1, off, 64);
        }
        if (lane == 0) {
            out[row0] = a0 + bias[row0];
            out[row1] = a1 + bias[row1];
        }
    }
}

extern "C" void kernel_launch(void* const* d_in, const int* in_sizes, int n_in,
                              void* d_out, int out_size, void* d_ws, size_t ws_size,
                              hipStream_t stream) {
    const float* x      = (const float*)d_in[0];
    const float* W      = (const float*)d_in[1];
    const float* bias   = (const float*)d_in[2];
    const int*   cached = (const int*)d_in[3];
    float* out = (float*)d_out;

    char* ws = (char*)d_ws;
    unsigned* maskbits = (unsigned*)(ws + 0);
    unsigned* score    = (unsigned*)(ws + 1472);
    unsigned* flag     = (unsigned*)(ws + 1476);
    unsigned* done     = (unsigned*)(ws + 1480);

    hipMemsetAsync(ws + 1472, 0, 12, stream);   // score, flag, done
    k_all<<<NBLK, NTHR, 0, stream>>>(x, W, bias, cached, out,
                                     maskbits, score, flag, done);
}

// Round 6
// 264.847 us; speedup vs baseline: 1.2612x; 1.0026x over previous
//
#include <hip/hip_runtime.h>
#include <stdint.h>

#define IN_F   11008
#define OUT_F  4096
#define TOPK_K 5504
#define NCACHE 64
#define MASK_WORDS 344   // 11008 / 32
#define NTHR   512
#define NCHUNK 22        // ceil(11008 / 512)
#define ROWS_PER_BLOCK 16
#define NGEMV  (OUT_F / ROWS_PER_BLOCK)   // 256
#define NBLK   (1 + NCACHE + NGEMV)       // 321

// ws layout (bytes):
//   [0    , 1376) : topk mask bits (344 u32)
//   [1472 , 1476) : packed score u32, atomicMax of (inter<<6)|(63-row)
//   [1476 , 1480) : mask-ready flag (release by block 0)
//   [1480 , 1484) : recall-done counter
// (score/flag/done zeroed by hipMemsetAsync before launch)

__device__ __forceinline__ unsigned absbits(float v) {
    return __float_as_uint(v) & 0x7fffffffu;
}

// ---------------------------------------------------------------------------
// Single fused kernel, 321 blocks x 512 threads, all co-resident by resource
// math (LDS 54.8KB -> 2 blocks/CU; VGPR<=128 via launch_bounds -> 16 waves/CU).
//   block 0      : exact radix-select + mask build, then release mask flag.
//                  x ingested via 6 batched float4 loads -> LDS -> strided
//                  re-read (ONE congested-HBM latency hit instead of 22 while
//                  prefetchers saturate the queues).
//   blocks 1..64 : build rowbits for cached row (bid-1) during select shadow,
//                  acquire flag, intersect -> packed atomicMax score,
//                  release-increment done.
//   blocks 65..320: prefetch own 16-row W slice (stop on flag), acquire flag,
//                  xs = mask.*x, GEMV 2 rows/wave (verified loop), spin
//                  done==64, epilogue (mask path or rare exact cached path).
// Dependency DAG acyclic; no reliance on dispatch order.
// ---------------------------------------------------------------------------
__global__ __launch_bounds__(NTHR, 4) void k_all(const float* __restrict__ x,
                                                 const float* __restrict__ W,
                                                 const float* __restrict__ bias,
                                                 const int* __restrict__ cached,
                                                 float* __restrict__ out,
                                                 unsigned* __restrict__ maskbits_g,
                                                 unsigned* __restrict__ score_g,
                                                 unsigned* __restrict__ flag_g,
                                                 unsigned* __restrict__ done_g) {
    __shared__ unsigned hist[8][256];    // select: per-wave private hists (8KB)
    __shared__ unsigned csum[256];
    __shared__ unsigned sh_T, sh_rem, sh_totEq;
    __shared__ unsigned waveEq[NCHUNK][8];
    __shared__ unsigned waveEqPre[NCHUNK][8];
    __shared__ unsigned rowbits[MASK_WORDS];   // recall
    __shared__ unsigned wsum[8];
    __shared__ __align__(16) float xs[IN_F];   // gemv (44KB); select reuses as x stage

    const int tid  = threadIdx.x;
    const int wv   = tid >> 6;
    const int lane = tid & 63;
    const int bid  = blockIdx.x;

    // ===================== block 0: radix-select =====================
    if (bid == 0) {
        // batched x ingest: 6 independent float4 loads issued together -> one
        // latency hit under prefetch-congested HBM; stage to LDS, read strided.
        {
            float4* xs4w = (float4*)xs;
#pragma unroll
            for (int k = 0; k < 6; ++k) {
                int j = k * NTHR + tid;
                if (j < IN_F / 4) xs4w[j] = ((const float4*)x)[j];
            }
        }
        __syncthreads();

        const int nk = (tid < 256) ? NCHUNK : NCHUNK - 1;   // 11008 = 21*512 + 256

        unsigned key[NCHUNK];
#pragma unroll
        for (int c = 0; c < NCHUNK; ++c) {
            key[c] = 0u;
            if (c < nk) key[c] = absbits(xs[c * NTHR + tid]);
        }
        __syncthreads();   // xs dead after this (block 0 never builds gemv xs)

        unsigned prefix = 0, maskHi = 0, remaining = TOPK_K;

        for (int pass = 3; pass >= 0; --pass) {
            const int sh = pass * 8;
            for (int b = tid; b < 8 * 256; b += NTHR) ((unsigned*)hist)[b] = 0;
            __syncthreads();
#pragma unroll
            for (int c = 0; c < NCHUNK; ++c) {
                if (c < nk && (key[c] & maskHi) == prefix)
                    atomicAdd(&hist[wv][(key[c] >> sh) & 255], 1u);
            }
            __syncthreads();
            if (tid < 256) {          // merge 8 hists, conflict-free
                unsigned s = 0;
#pragma unroll
                for (int w = 0; w < 8; ++w) s += hist[w][tid];
                csum[tid] = s;
            }
            __syncthreads();
            if (wv == 0) {
                // lane l owns buckets [4l,4l+4); inclusive suffix-scan across lanes
                unsigned c0 = csum[4 * lane + 0], c1 = csum[4 * lane + 1];
                unsigned c2 = csum[4 * lane + 2], c3 = csum[4 * lane + 3];
                unsigned S = c0 + c1 + c2 + c3;
#pragma unroll
                for (int off = 1; off < 64; off <<= 1) {
                    unsigned v = __shfl_down(S, off, 64);
                    if (lane + off < 64) S += v;
                }
                unsigned Sn = __shfl_down(S, 1, 64);
                if (lane == 63) Sn = 0;
                unsigned t3 = Sn + c3;
                unsigned t2 = t3 + c2;
                unsigned t1 = t2 + c1;
                unsigned t0 = t1 + c0;
                unsigned rem = remaining;
                if (t3 >= rem && Sn < rem) { sh_T = prefix | ((unsigned)(4 * lane + 3) << sh); sh_rem = rem - Sn; }
                if (t2 >= rem && t3 < rem) { sh_T = prefix | ((unsigned)(4 * lane + 2) << sh); sh_rem = rem - t3; }
                if (t1 >= rem && t2 < rem) { sh_T = prefix | ((unsigned)(4 * lane + 1) << sh); sh_rem = rem - t2; }
                if (t0 >= rem && t1 < rem) { sh_T = prefix | ((unsigned)(4 * lane + 0) << sh); sh_rem = rem - t1; }
            }
            __syncthreads();
            prefix = sh_T;
            maskHi |= 0xffu << sh;
            remaining = sh_rem;
        }

        const unsigned T = prefix;
        const unsigned eqTake = remaining;

        unsigned gtm = 0, eqm = 0;
#pragma unroll
        for (int c = 0; c < NCHUNK; ++c) {
            if (c < nk) {
                if (key[c] > T)       gtm |= 1u << c;
                else if (key[c] == T) eqm |= 1u << c;
            }
        }
#pragma unroll
        for (int c = 0; c < NCHUNK; ++c) {
            unsigned long long bal = __ballot((eqm >> c) & 1u);
            if (lane == 0) waveEq[c][wv] = (unsigned)__popcll(bal);
        }
        __syncthreads();
        if (tid < 64) {
            unsigned s = 0;
            for (int p = lane; p < NCHUNK * 8; p += 64) s += waveEq[p >> 3][p & 7];
#pragma unroll
            for (int off = 32; off > 0; off >>= 1) s += __shfl_down(s, off, 64);
            if (lane == 0) sh_totEq = s;
        }
        __syncthreads();
        const bool fast = (sh_totEq == eqTake);
        if (!fast) {
            if (tid == 0) {
                unsigned run = 0;
                for (int c = 0; c < NCHUNK; ++c)
                    for (int w = 0; w < 8; ++w) { waveEqPre[c][w] = run; run += waveEq[c][w]; }
            }
            __syncthreads();
        }
#pragma unroll
        for (int c = 0; c < NCHUNK; ++c) {
            bool eq = (eqm >> c) & 1u;
            bool take;
            if (fast) {
                take = (((gtm >> c) & 1u) != 0u) || eq;
            } else {
                unsigned long long balEq = __ballot(eq);
                unsigned rank = waveEqPre[c][wv] + (unsigned)__popcll(balEq & ((1ull << lane) - 1ull));
                take = (((gtm >> c) & 1u) != 0u) || (eq && rank < eqTake);
            }
            unsigned long long balT = __ballot(take);
            int w0 = c * 16 + wv * 2;          // chunk c covers words [c*16, c*16+16)
            if (w0 < MASK_WORDS && lane == 0) {
                maskbits_g[w0]     = (unsigned)balT;
                maskbits_g[w0 + 1] = (unsigned)(balT >> 32);
            }
        }
        __syncthreads();
        if (tid == 0) {
            __threadfence();   // make maskbits visible device-wide, then release flag
            __hip_atomic_store(flag_g, 1u, __ATOMIC_RELEASE, __HIP_MEMORY_SCOPE_AGENT);
        }
        return;
    }

    // ===================== blocks 1..64: recall =====================
    if (bid <= NCACHE) {
        const int r = bid - 1;
        // build rowbits during the select shadow (mask-independent)
        for (int w = tid; w < MASK_WORDS; w += NTHR) rowbits[w] = 0;
        __syncthreads();
        const int4* ci4 = (const int4*)(cached + (size_t)r * TOPK_K);
        for (int t = tid; t < TOPK_K / 4; t += NTHR) {
            int4 v = ci4[t];
            atomicOr(&rowbits[v.x >> 5], 1u << (v.x & 31));
            atomicOr(&rowbits[v.y >> 5], 1u << (v.y & 31));
            atomicOr(&rowbits[v.z >> 5], 1u << (v.z & 31));
            atomicOr(&rowbits[v.w >> 5], 1u << (v.w & 31));
        }
        __syncthreads();
        if (tid == 0) {
            while (__hip_atomic_load(flag_g, __ATOMIC_ACQUIRE, __HIP_MEMORY_SCOPE_AGENT) == 0u)
                __builtin_amdgcn_s_sleep(8);
        }
        __syncthreads();
        unsigned cnt = 0;
        for (int w = tid; w < MASK_WORDS; w += NTHR) cnt += __popc(rowbits[w] & maskbits_g[w]);
        for (int off = 32; off > 0; off >>= 1) cnt += __shfl_down(cnt, off, 64);
        if (lane == 0) wsum[wv] = cnt;
        __syncthreads();
        if (tid == 0) {
            unsigned tot = 0;
#pragma unroll
            for (int w = 0; w < 8; ++w) tot += wsum[w];
            atomicMax(score_g, (tot << 6) | (unsigned)(63 - r));
            __hip_atomic_fetch_add(done_g, 1u, __ATOMIC_RELEASE, __HIP_MEMORY_SCOPE_AGENT);
        }
        return;
    }

    // ===================== blocks 65..320: GEMV =====================
    const int g = bid - 1 - NCACHE;                  // 0..255
    const float4* wp = (const float4*)(W + (size_t)g * (ROWS_PER_BLOCK * IN_F));

    // prefetch own W slice into L2/L3 while select runs (stop on flag; hint only)
    {
        const int NCH = (ROWS_PER_BLOCK * IN_F / 4) / (2 * NTHR);   // 43 chunks of 16KB
        for (int c = 0; c < NCH; ++c) {
            if (c >= 1 && __hip_atomic_load(flag_g, __ATOMIC_RELAXED, __HIP_MEMORY_SCOPE_AGENT) != 0u)
                break;
            float4 a = wp[c * 2 * NTHR + tid];
            float4 b = wp[c * 2 * NTHR + NTHR + tid];
            asm volatile("" :: "v"(a.x), "v"(a.y), "v"(a.z), "v"(a.w));
            asm volatile("" :: "v"(b.x), "v"(b.y), "v"(b.z), "v"(b.w));
        }
    }

    // wait for mask
    if (tid == 0) {
        while (__hip_atomic_load(flag_g, __ATOMIC_ACQUIRE, __HIP_MEMORY_SCOPE_AGENT) == 0u)
            __builtin_amdgcn_s_sleep(8);
    }
    __syncthreads();

    // xs = mask .* x (speculative topk path)
    {
        const float4* x4 = (const float4*)x;
        for (int j = tid; j < IN_F / 4; j += NTHR) {
            float4 xv = x4[j];
            int base = j * 4;
            unsigned wbits = maskbits_g[base >> 5];
            int sh = base & 31;
            xs[base + 0] = xv.x * (float)((wbits >> (sh + 0)) & 1u);
            xs[base + 1] = xv.y * (float)((wbits >> (sh + 1)) & 1u);
            xs[base + 2] = xv.z * (float)((wbits >> (sh + 2)) & 1u);
            xs[base + 3] = xv.w * (float)((wbits >> (sh + 3)) & 1u);
        }
    }
    __syncthreads();

    const int row0 = g * ROWS_PER_BLOCK + wv * 2;
    const int row1 = row0 + 1;
    const float4* w0p = (const float4*)(W + (size_t)row0 * IN_F);
    const float4* w1p = (const float4*)(W + (size_t)row1 * IN_F);
    const float4* xs4 = (const float4*)xs;

    float acc0 = 0.f, acc1 = 0.f;
#pragma unroll 4
    for (int j = lane; j < IN_F / 4; j += 64) {   // exactly 43 iters/lane
        float4 xv = xs4[j];
        float4 a  = w0p[j];
        float4 b  = w1p[j];
        acc0 += xv.x * a.x + xv.y * a.y + xv.z * a.z + xv.w * a.w;
        acc1 += xv.x * b.x + xv.y * b.y + xv.z * b.z + xv.w * b.w;
    }
    for (int off = 32; off > 0; off >>= 1) {
        acc0 += __shfl_down(acc0, off, 64);
        acc1 += __shfl_down(acc1, off, 64);
    }

    // wait for all 64 recall blocks (finished long ago in practice)
    if (tid == 0) {
        while (__hip_atomic_load(done_g, __ATOMIC_ACQUIRE, __HIP_MEMORY_SCOPE_AGENT) < NCACHE)
            __builtin_amdgcn_s_sleep(2);
    }
    __syncthreads();

    unsigned score = *score_g;
    bool useCache = ((float)(score >> 6) / (float)TOPK_K) >= 0.9f;
    if (!useCache) {
        if (lane == 0) {
            out[row0] = acc0 + bias[row0];
            out[row1] = acc1 + bias[row1];
        }
    } else {
        // rare exact path: xs[i] = multiplicity(i in best row) * x[i]
        int best = 63 - (int)(score & 63u);
        __syncthreads();
        for (int i = tid; i < IN_F; i += NTHR) xs[i] = 0.f;
        __syncthreads();
        const int* ci = cached + (size_t)best * TOPK_K;
        for (int t = tid; t < TOPK_K; t += NTHR) {
            int idx = ci[t];
            atomicAdd(&xs[idx], x[idx]);   // duplicates accumulate -> count*x
        }
        __syncthreads();
        float a0 = 0.f, a1 = 0.f;
#pragma unroll 4
        for (int j = lane; j < IN_F / 4; j += 64) {
            float4 xv = xs4[j];
            float4 a  = w0p[j];
            float4 b  = w1p[j];
            a0 += xv.x * a.x + xv.y * a.y + xv.z * a.z + xv.w * a.w;
            a1 += xv.x * b.x + xv.y * b.y + xv.z * b.z + xv.w * b.w;
        }
        for (int off = 32; off > 0; off >>= 1) {
            a0 += __shfl_down(a0, off, 64);
            a1 += __shfl_down(a1, off, 64);
        }
        if (lane == 0) {
            out[row0] = a0 + bias[row0];
            out[row1] = a1 + bias[row1];
        }
    }
}

extern "C" void kernel_launch(void* const* d_in, const int* in_sizes, int n_in,
                              void* d_out, int out_size, void* d_ws, size_t ws_size,
                              hipStream_t stream) {
    const float* x      = (const float*)d_in[0];
    const float* W      = (const float*)d_in[1];
    const float* bias   = (const float*)d_in[2];
    const int*   cached = (const int*)d_in[3];
    float* out = (float*)d_out;

    char* ws = (char*)d_ws;
    unsigned* maskbits = (unsigned*)(ws + 0);
    unsigned* score    = (unsigned*)(ws + 1472);
    unsigned* flag     = (unsigned*)(ws + 1476);
    unsigned* done     = (unsigned*)(ws + 1480);

    hipMemsetAsync(ws + 1472, 0, 12, stream);   // score, flag, done
    k_all<<<NBLK, NTHR, 0, stream>>>(x, W, bias, cached, out,
                                     maskbits, score, flag, done);
}

// Round 8
// 264.023 us; speedup vs baseline: 1.2652x; 1.0031x over previous
//
#include <hip/hip_runtime.h>
#include <stdint.h>

#define IN_F   11008
#define OUT_F  4096
#define TOPK_K 5504
#define NCACHE 64
#define MASK_WORDS 344   // 11008 / 32
#define NTHR   512
#define NCHUNK 22        // ceil(11008 / 512)
#define ROWS_PER_BLOCK 16
#define NWORK  (OUT_F / ROWS_PER_BLOCK)   // 256 worker blocks, 1 per CU
#define NBLK   (1 + NWORK)                // 257

// ws layout (bytes):
//   [0    , 1376) : topk mask bits (344 u32)
//   [1472 , 1476) : packed score u32, atomicMax of (inter<<6)|(63-row)
//   [1476 , 1480) : mask-ready flag (release by block 0)
//   [1480 , 1484) : recall-done counter
// (score/flag/done zeroed by hipMemsetAsync before launch)

__device__ __forceinline__ unsigned absbits(float v) {
    return __float_as_uint(v) & 0x7fffffffu;
}

// ---------------------------------------------------------------------------
// Single fused kernel, 257 blocks x 512 threads (1 worker block per CU —
// uniform 16-row W slice each; R6's 321-block layout doubled 65 CUs and
// created an ~10us straggler tail).
//   block 0      : exact radix-select + mask build (verified), release flag,
//                  return. Compute-light; shares a CU with one worker.
//   workers 1..256 (g = bid-1, W rows [g*16,(g+1)*16)):
//       bid<=64 : build rowbits for cached row g (mask-independent)
//       all     : prefetch own W slice into L2/L3 until flag (hint only)
//       all     : acquire flag
//       bid<=64 : intersect rowbits & mask -> packed atomicMax score, done++
//       all     : xs = mask.*x, GEMV 2 rows/wave (verified loop),
//                 spin done==64, epilogue (mask path or rare exact cached path)
// Dependency DAG acyclic; all 257 blocks co-resident by resource math
// (LDS ~55.5KB -> 2 blocks/CU; VGPR<=128 via launch_bounds -> 16 waves/CU).
// ---------------------------------------------------------------------------
__global__ __launch_bounds__(NTHR, 4) void k_all(const float* __restrict__ x,
                                                 const float* __restrict__ W,
                                                 const float* __restrict__ bias,
                                                 const int* __restrict__ cached,
                                                 float* __restrict__ out,
                                                 unsigned* __restrict__ maskbits_g,
                                                 unsigned* __restrict__ score_g,
                                                 unsigned* __restrict__ flag_g,
                                                 unsigned* __restrict__ done_g) {
    __shared__ unsigned hist[8][256];    // select: per-wave private hists (8KB)
    __shared__ unsigned csum[256];
    __shared__ unsigned sh_T, sh_rem, sh_totEq;
    __shared__ unsigned waveEq[NCHUNK][8];
    __shared__ unsigned waveEqPre[NCHUNK][8];
    __shared__ unsigned rowbits[MASK_WORDS];   // recall
    __shared__ unsigned wsum[8];
    __shared__ __align__(16) float xs[IN_F];   // gemv (44KB); select reuses as x stage

    const int tid  = threadIdx.x;
    const int wv   = tid >> 6;
    const int lane = tid & 63;
    const int bid  = blockIdx.x;

    // ===================== block 0: radix-select =====================
    if (bid == 0) {
        // batched x ingest: 6 independent float4 loads -> LDS -> strided re-read
        {
            float4* xs4w = (float4*)xs;
#pragma unroll
            for (int k = 0; k < 6; ++k) {
                int j = k * NTHR + tid;
                if (j < IN_F / 4) xs4w[j] = ((const float4*)x)[j];
            }
        }
        __syncthreads();

        const int nk = (tid < 256) ? NCHUNK : NCHUNK - 1;   // 11008 = 21*512 + 256

        unsigned key[NCHUNK];
#pragma unroll
        for (int c = 0; c < NCHUNK; ++c) {
            key[c] = 0u;
            if (c < nk) key[c] = absbits(xs[c * NTHR + tid]);
        }
        __syncthreads();

        unsigned prefix = 0, maskHi = 0, remaining = TOPK_K;

        for (int pass = 3; pass >= 0; --pass) {
            const int sh = pass * 8;
            for (int b = tid; b < 8 * 256; b += NTHR) ((unsigned*)hist)[b] = 0;
            __syncthreads();
#pragma unroll
            for (int c = 0; c < NCHUNK; ++c) {
                if (c < nk && (key[c] & maskHi) == prefix)
                    atomicAdd(&hist[wv][(key[c] >> sh) & 255], 1u);
            }
            __syncthreads();
            if (tid < 256) {          // merge 8 hists, conflict-free
                unsigned s = 0;
#pragma unroll
                for (int w = 0; w < 8; ++w) s += hist[w][tid];
                csum[tid] = s;
            }
            __syncthreads();
            if (wv == 0) {
                // lane l owns buckets [4l,4l+4); inclusive suffix-scan across lanes
                unsigned c0 = csum[4 * lane + 0], c1 = csum[4 * lane + 1];
                unsigned c2 = csum[4 * lane + 2], c3 = csum[4 * lane + 3];
                unsigned S = c0 + c1 + c2 + c3;
#pragma unroll
                for (int off = 1; off < 64; off <<= 1) {
                    unsigned v = __shfl_down(S, off, 64);
                    if (lane + off < 64) S += v;
                }
                unsigned Sn = __shfl_down(S, 1, 64);
                if (lane == 63) Sn = 0;
                unsigned t3 = Sn + c3;
                unsigned t2 = t3 + c2;
                unsigned t1 = t2 + c1;
                unsigned t0 = t1 + c0;
                unsigned rem = remaining;
                if (t3 >= rem && Sn < rem) { sh_T = prefix | ((unsigned)(4 * lane + 3) << sh); sh_rem = rem - Sn; }
                if (t2 >= rem && t3 < rem) { sh_T = prefix | ((unsigned)(4 * lane + 2) << sh); sh_rem = rem - t3; }
                if (t1 >= rem && t2 < rem) { sh_T = prefix | ((unsigned)(4 * lane + 1) << sh); sh_rem = rem - t2; }
                if (t0 >= rem && t1 < rem) { sh_T = prefix | ((unsigned)(4 * lane + 0) << sh); sh_rem = rem - t1; }
            }
            __syncthreads();
            prefix = sh_T;
            maskHi |= 0xffu << sh;
            remaining = sh_rem;
        }

        const unsigned T = prefix;
        const unsigned eqTake = remaining;

        unsigned gtm = 0, eqm = 0;
#pragma unroll
        for (int c = 0; c < NCHUNK; ++c) {
            if (c < nk) {
                if (key[c] > T)       gtm |= 1u << c;
                else if (key[c] == T) eqm |= 1u << c;
            }
        }
#pragma unroll
        for (int c = 0; c < NCHUNK; ++c) {
            unsigned long long bal = __ballot((eqm >> c) & 1u);
            if (lane == 0) waveEq[c][wv] = (unsigned)__popcll(bal);
        }
        __syncthreads();
        if (tid < 64) {
            unsigned s = 0;
            for (int p = lane; p < NCHUNK * 8; p += 64) s += waveEq[p >> 3][p & 7];
#pragma unroll
            for (int off = 32; off > 0; off >>= 1) s += __shfl_down(s, off, 64);
            if (lane == 0) sh_totEq = s;
        }
        __syncthreads();
        const bool fast = (sh_totEq == eqTake);
        if (!fast) {
            if (tid == 0) {
                unsigned run = 0;
                for (int c = 0; c < NCHUNK; ++c)
                    for (int w = 0; w < 8; ++w) { waveEqPre[c][w] = run; run += waveEq[c][w]; }
            }
            __syncthreads();
        }
#pragma unroll
        for (int c = 0; c < NCHUNK; ++c) {
            bool eq = (eqm >> c) & 1u;
            bool take;
            if (fast) {
                take = (((gtm >> c) & 1u) != 0u) || eq;
            } else {
                unsigned long long balEq = __ballot(eq);
                unsigned rank = waveEqPre[c][wv] + (unsigned)__popcll(balEq & ((1ull << lane) - 1ull));
                take = (((gtm >> c) & 1u) != 0u) || (eq && rank < eqTake);
            }
            unsigned long long balT = __ballot(take);
            int w0 = c * 16 + wv * 2;          // chunk c covers words [c*16, c*16+16)
            if (w0 < MASK_WORDS && lane == 0) {
                maskbits_g[w0]     = (unsigned)balT;
                maskbits_g[w0 + 1] = (unsigned)(balT >> 32);
            }
        }
        __syncthreads();
        if (tid == 0) {
            __threadfence();   // make maskbits visible device-wide, then release flag
            __hip_atomic_store(flag_g, 1u, __ATOMIC_RELEASE, __HIP_MEMORY_SCOPE_AGENT);
        }
        return;
    }

    // ===================== workers 1..256 =====================
    const int g = bid - 1;                           // 0..255; W rows [g*16,(g+1)*16)
    const float4* wp = (const float4*)(W + (size_t)g * (ROWS_PER_BLOCK * IN_F));
    const bool doRecall = (g < NCACHE);

    if (doRecall) {
        // build rowbits for cached row g during the select shadow (mask-independent)
        for (int w = tid; w < MASK_WORDS; w += NTHR) rowbits[w] = 0;
        __syncthreads();
        const int4* ci4 = (const int4*)(cached + (size_t)g * TOPK_K);
        for (int t = tid; t < TOPK_K / 4; t += NTHR) {
            int4 v = ci4[t];
            atomicOr(&rowbits[v.x >> 5], 1u << (v.x & 31));
            atomicOr(&rowbits[v.y >> 5], 1u << (v.y & 31));
            atomicOr(&rowbits[v.z >> 5], 1u << (v.z & 31));
            atomicOr(&rowbits[v.w >> 5], 1u << (v.w & 31));
        }
        __syncthreads();
    }

    // prefetch own W slice into L2/L3 while select runs (stop on flag; hint only)
    {
        const int NCH = (ROWS_PER_BLOCK * IN_F / 4) / (2 * NTHR);   // 43 chunks of 16KB
        for (int c = 0; c < NCH; ++c) {
            if (c >= 1 && __hip_atomic_load(flag_g, __ATOMIC_RELAXED, __HIP_MEMORY_SCOPE_AGENT) != 0u)
                break;
            float4 a = wp[c * 2 * NTHR + tid];
            float4 b = wp[c * 2 * NTHR + NTHR + tid];
            asm volatile("" :: "v"(a.x), "v"(a.y), "v"(a.z), "v"(a.w));
            asm volatile("" :: "v"(b.x), "v"(b.y), "v"(b.z), "v"(b.w));
        }
    }

    // wait for mask
    if (tid == 0) {
        while (__hip_atomic_load(flag_g, __ATOMIC_ACQUIRE, __HIP_MEMORY_SCOPE_AGENT) == 0u)
            __builtin_amdgcn_s_sleep(8);
    }
    __syncthreads();

    if (doRecall) {   // intersect -> score for cached row g
        unsigned cnt = 0;
        for (int w = tid; w < MASK_WORDS; w += NTHR) cnt += __popc(rowbits[w] & maskbits_g[w]);
        for (int off = 32; off > 0; off >>= 1) cnt += __shfl_down(cnt, off, 64);
        if (lane == 0) wsum[wv] = cnt;
        __syncthreads();
        if (tid == 0) {
            unsigned tot = 0;
#pragma unroll
            for (int w = 0; w < 8; ++w) tot += wsum[w];
            atomicMax(score_g, (tot << 6) | (unsigned)(63 - g));
            __hip_atomic_fetch_add(done_g, 1u, __ATOMIC_RELEASE, __HIP_MEMORY_SCOPE_AGENT);
        }
    }

    // xs = mask .* x (speculative topk path)
    {
        const float4* x4 = (const float4*)x;
        for (int j = tid; j < IN_F / 4; j += NTHR) {
            float4 xv = x4[j];
            int base = j * 4;
            unsigned wbits = maskbits_g[base >> 5];
            int sh = base & 31;
            xs[base + 0] = xv.x * (float)((wbits >> (sh + 0)) & 1u);
            xs[base + 1] = xv.y * (float)((wbits >> (sh + 1)) & 1u);
            xs[base + 2] = xv.z * (float)((wbits >> (sh + 2)) & 1u);
            xs[base + 3] = xv.w * (float)((wbits >> (sh + 3)) & 1u);
        }
    }
    __syncthreads();

    const int row0 = g * ROWS_PER_BLOCK + wv * 2;
    const int row1 = row0 + 1;
    const float4* w0p = (const float4*)(W + (size_t)row0 * IN_F);
    const float4* w1p = (const float4*)(W + (size_t)row1 * IN_F);
    const float4* xs4 = (const float4*)xs;

    float acc0 = 0.f, acc1 = 0.f;
#pragma unroll 4
    for (int j = lane; j < IN_F / 4; j += 64) {   // exactly 43 iters/lane
        float4 xv = xs4[j];
        float4 a  = w0p[j];
        float4 b  = w1p[j];
        acc0 += xv.x * a.x + xv.y * a.y + xv.z * a.z + xv.w * a.w;
        acc1 += xv.x * b.x + xv.y * b.y + xv.z * b.z + xv.w * b.w;
    }
    for (int off = 32; off > 0; off >>= 1) {
        acc0 += __shfl_down(acc0, off, 64);
        acc1 += __shfl_down(acc1, off, 64);
    }

    // wait for all 64 recall publishers (finished long ago in practice)
    if (tid == 0) {
        while (__hip_atomic_load(done_g, __ATOMIC_ACQUIRE, __HIP_MEMORY_SCOPE_AGENT) < NCACHE)
            __builtin_amdgcn_s_sleep(2);
    }
    __syncthreads();

    unsigned score = *score_g;
    bool useCache = ((float)(score >> 6) / (float)TOPK_K) >= 0.9f;
    if (!useCache) {
        if (lane == 0) {
            out[row0] = acc0 + bias[row0];
            out[row1] = acc1 + bias[row1];
        }
    } else {
        // rare exact path: xs[i] = multiplicity(i in best row) * x[i]
        int best = 63 - (int)(score & 63u);
        __syncthreads();
        for (int i = tid; i < IN_F; i += NTHR) xs[i] = 0.f;
        __syncthreads();
        const int* ci = cached + (size_t)best * TOPK_K;
        for (int t = tid; t < TOPK_K; t += NTHR) {
            int idx = ci[t];
            atomicAdd(&xs[idx], x[idx]);   // duplicates accumulate -> count*x
        }
        __syncthreads();
        float a0 = 0.f, a1 = 0.f;
#pragma unroll 4
        for (int j = lane; j < IN_F / 4; j += 64) {
            float4 xv = xs4[j];
            float4 a  = w0p[j];
            float4 b  = w1p[j];
            a0 += xv.x * a.x + xv.y * a.y + xv.z * a.z + xv.w * a.w;
            a1 += xv.x * b.x + xv.y * b.y + xv.z * b.z + xv.w * b.w;
        }
        for (int off = 32; off > 0; off >>= 1) {
            a0 += __shfl_down(a0, off, 64);
            a1 += __shfl_down(a1, off, 64);
        }
        if (lane == 0) {
            out[row0] = a0 + bias[row0];
            out[row1] = a1 + bias[row1];
        }
    }
}

extern "C" void kernel_launch(void* const* d_in, const int* in_sizes, int n_in,
                              void* d_out, int out_size, void* d_ws, size_t ws_size,
                              hipStream_t stream) {
    const float* x      = (const float*)d_in[0];
    const float* W      = (const float*)d_in[1];
    const float* bias   = (const float*)d_in[2];
    const int*   cached = (const int*)d_in[3];
    float* out = (float*)d_out;

    char* ws = (char*)d_ws;
    unsigned* maskbits = (unsigned*)(ws + 0);
    unsigned* score    = (unsigned*)(ws + 1472);
    unsigned* flag     = (unsigned*)(ws + 1476);
    unsigned* done     = (unsigned*)(ws + 1480);

    hipMemsetAsync(ws + 1472, 0, 12, stream);   // score, flag, done
    k_all<<<NBLK, NTHR, 0, stream>>>(x, W, bias, cached, out,
                                     maskbits, score, flag, done);
}